// Round 1
// 202.136 us; speedup vs baseline: 1.0462x; 1.0462x over previous
//
#include <hip/hip_runtime.h>
#include <math.h>

// Problem constants
#define B_  4
#define S_  2048
#define H_  1024
#define D_  64
#define ROWS (B_*S_)      // 8192
#define KSPLIT 8
#define LOG2E 1.4426950408889634f

typedef __attribute__((ext_vector_type(4))) float  floatx4;
typedef __attribute__((ext_vector_type(8))) short  short8;
typedef __attribute__((ext_vector_type(8))) __bf16 bf16x8;

// ---- workspace layout ----
// float region (offsets in floats):
#define WS_KSUM 0                          // [B][D]
#define WS_M    (WS_KSUM + B_*D_)          // [B][D][D]  K^T K per batch
#define WS_A2   (WS_M + B_*D_*D_)          // ROWS  inv/32*log2e
#define WS_C2   (WS_A2 + ROWS)             // ROWS  -mu*inv*log2e
#define WS_SWP  (WS_C2 + ROWS)             // [KSPLIT][ROWS] sumw partials
#define WS_FEND (WS_SWP + KSPLIT*ROWS)     // floats (x4 B = 16B-aligned)
// bf16(short) region, starts right after the float region.
#define WB_QB  0                           // [ROWS][64] row-major (rowstats + attn Q-frags)
#define WB_KF  (WB_QB + ROWS*D_)           // [ROWS/16][kh2][64][8]  K A-frags
#define WB_VF  (WB_KF + ROWS*D_)           // [ROWS/64][nt4][kh2][64][8]  V B-frags
#define WB_WT  (WB_VF + ROWS*D_)           // [3][32 kc][4 nt][64][8]  W B-frags
#define WB_WFF (WB_WT + 3*D_*H_)           // [H/16][2][64][8]  Weff B-frags
#define WB_OP  (WB_WFF + H_*D_)            // [KSPLIT][ROWS][64] O partials bf16
#define NZ2    (B_*D_ + B_*D_*D_)          // zeroed atomically-accumulated range

__device__ __forceinline__ unsigned short f2bf(float f) {
    union { float f; unsigned u; } v; v.f = f;
    unsigned r = v.u + 0x7FFFu + ((v.u >> 16) & 1u);   // RNE
    return (unsigned short)(r >> 16);
}
__device__ __forceinline__ short bfc(float f) {        // HW cvt (RNE) path
    __bf16 h = (__bf16)f;
    short s; __builtin_memcpy(&s, &h, 2); return s;
}
__device__ __forceinline__ float bf2f(short s) {
    union { unsigned u; float f; } v;
    v.u = ((unsigned)(unsigned short)s) << 16; return v.f;
}
__device__ __forceinline__ bf16x8 ldb(const short* p) {
    union { short8 s; bf16x8 b; } u; u.s = *(const short8*)p; return u.b;
}
#define MFMA(a,b,c) __builtin_amdgcn_mfma_f32_16x16x32_bf16(a, b, c, 0, 0, 0)
// per-wave LDS ordering fence: lgkmcnt(0) only, vmcnt stays in flight
__device__ __forceinline__ void lds_fence() {
    __builtin_amdgcn_wave_barrier();
    __builtin_amdgcn_s_waitcnt(0xc07f);
    __builtin_amdgcn_wave_barrier();
}

// ---------------------------------------------------------------------------
// 1) prep:
//    bx [0,96):    WT3 fragment-major gather of Wq/Wk/Wv (bf16)
//    bx [96,112):  WFF = fragment-major bf16 of Weff^T (sum of Wout blocks)
//    bx [112,177): zero KSUM+M
__global__ __launch_bounds__(256) void prep(
    const float* __restrict__ Wq, const float* __restrict__ Wk,
    const float* __restrict__ Wv, const float* __restrict__ Wout,
    float* __restrict__ wsf)
{
    __shared__ float tile[64][65];
    short* wsb = (short*)(wsf + WS_FEND);
    const int bx = blockIdx.x, t = threadIdx.x;
    if (bx < 96) {
        int idx = bx * 256 + t;              // slot < 3*32*4*64
        int mat = idx >> 13, rem = idx & 8191;
        int kc = rem >> 8, nt = (rem >> 6) & 3, lane = rem & 63;
        int g = lane >> 4, l15 = lane & 15;
        const float* W = (mat == 0) ? Wq : (mat == 1) ? Wk : Wv;
        short8 fr;
        #pragma unroll
        for (int j = 0; j < 8; ++j)
            fr[j] = (short)f2bf(W[(size_t)(kc*32 + g*8 + j) * D_ + nt*16 + l15]);
        *(short8*)&wsb[WB_WT + (size_t)idx * 8] = fr;
    } else if (bx < 112) {
        // Weff[d][n] = sum_h Wout[h*64+d][n]
        int n0 = (bx - 96) * 64;
        int nn = t & 63, dg = t >> 6;
        for (int dd = 0; dd < 16; ++dd) {
            int d = dg * 16 + dd;
            float s = 0.0f;
            #pragma unroll
            for (int h = 0; h < 16; ++h)
                s += Wout[(size_t)(h * 64 + d) * H_ + n0 + nn];
            tile[d][nn] = s;
        }
        __syncthreads();
        #pragma unroll
        for (int u = 0; u < 2; ++u) {
            int s = 2*t + u;                 // slot < 512
            int ctl = s >> 7, h = (s >> 6) & 1, lane = s & 63;
            int g = lane >> 4, l2 = lane & 15;
            short8 fr;
            #pragma unroll
            for (int j = 0; j < 8; ++j)
                fr[j] = (short)f2bf(tile[h*32 + g*8 + j][ctl*16 + l2]);
            *(short8*)&wsb[WB_WFF + (size_t)((((n0 >> 4) + ctl)*2 + h)*64 + lane) * 8] = fr;
        }
    } else {
        int i = (bx - 112) * 256 + t;
        if (i < NZ2) wsf[WS_KSUM + i] = 0.0f;
    }
}

// ---------------------------------------------------------------------------
// 2) q/k/v = bf16(X @ W + b) via MFMA.  grid (ROWS/32, 3), block 256.
__global__ __launch_bounds__(256) void qkv_mfma(
    const float* __restrict__ query, const float* __restrict__ key,
    const float* __restrict__ value,
    const float* __restrict__ bq, const float* __restrict__ bk,
    const float* __restrict__ bvp, float* __restrict__ wsf)
{
    short* wsb = (short*)(wsf + WS_FEND);
    const int mat = blockIdx.y;
    const float* X    = (mat == 0) ? query : (mat == 1) ? key : value;
    const float* bias = (mat == 0) ? bq    : (mat == 1) ? bk  : bvp;
    const short* WT3 = wsb + WB_WT + (size_t)mat * (D_ * H_);

    const int t = threadIdx.x, w = t >> 6, lane = t & 63;
    const int l15 = lane & 15, g = lane >> 4;
    const int r0 = blockIdx.x * 32;
    const int mrow0 = (w >> 1) * 16;
    const int nt0 = (w & 1) * 2;

    __shared__ short xs[32][136];   // bf16 X tile, stride 136: conflict-free family
    floatx4 acc[2] = {};

    for (int step = 0; step < 8; ++step) {
        __syncthreads();
        #pragma unroll
        for (int u = 0; u < 4; ++u) {
            int row = u * 8 + (t >> 5), col = (t & 31) * 4;
            float4 xv = *(const float4*)&X[(size_t)(r0 + row) * H_ + step * 128 + col];
            short4 pk;
            pk.x = bfc(xv.x); pk.y = bfc(xv.y); pk.z = bfc(xv.z); pk.w = bfc(xv.w);
            *(short4*)&xs[row][col] = pk;
        }
        __syncthreads();
        #pragma unroll
        for (int kk = 0; kk < 4; ++kk) {
            bf16x8 a = ldb(&xs[mrow0 + l15][kk * 32 + g * 8]);
            int kc = step * 4 + kk;
            #pragma unroll
            for (int n = 0; n < 2; ++n) {
                bf16x8 bf = ldb(&WT3[(size_t)((kc * 4) + nt0 + n) * 512 + lane * 8]);
                acc[n] = MFMA(a, bf, acc[n]);
            }
        }
    }

    // epilogue: C layout row=4g+r (in 16-tile), col=l15
    if (mat == 0) {
        short* QB = wsb + WB_QB;
        #pragma unroll
        for (int n = 0; n < 2; ++n) {
            int col = (nt0 + n) * 16 + l15;
            float bb = bias[col];
            #pragma unroll
            for (int r = 0; r < 4; ++r)
                QB[(size_t)(r0 + mrow0 + 4*g + r) * D_ + col] = (short)f2bf(acc[n][r] + bb);
        }
    } else if (mat == 1) {
        short* KF = wsb + WB_KF;
        #pragma unroll
        for (int n = 0; n < 2; ++n) {
            int d = (nt0 + n) * 16 + l15;
            int kh = d >> 5, gk = (d >> 3) & 3, j = d & 7;
            float bb = bias[d];
            #pragma unroll
            for (int r = 0; r < 4; ++r) {
                int R = r0 + mrow0 + 4*g + r;
                KF[(size_t)(((R >> 4) * 2 + kh) * 64 + gk * 16 + (R & 15)) * 8 + j] =
                    (short)f2bf(acc[n][r] + bb);
            }
        }
    } else {
        short* VF = wsb + WB_VF;
        int R0 = r0 + mrow0 + 4*g;
        int kh = (R0 >> 5) & 1, gv = (R0 >> 3) & 3, j0 = R0 & 7, blk = R0 >> 6;
        #pragma unroll
        for (int n = 0; n < 2; ++n) {
            int d = (nt0 + n) * 16 + l15;
            int ntv = d >> 4;
            float bb = bias[d];
            short4 pk;
            pk.x = (short)f2bf(acc[n][0] + bb); pk.y = (short)f2bf(acc[n][1] + bb);
            pk.z = (short)f2bf(acc[n][2] + bb); pk.w = (short)f2bf(acc[n][3] + bb);
            *(short4*)&VF[(size_t)(((blk * 4 + ntv) * 2 + kh) * 64 + gv * 16 + (d & 15)) * 8 + j0] = pk;
        }
    }
}

// ---------------------------------------------------------------------------
// 3) per-batch K column sums and M = K^T K (decodes KF fragments).
__global__ __launch_bounds__(256) void kstats(float* __restrict__ wsf) {
    const short* KF = (short*)(wsf + WS_FEND) + WB_KF;
    const int b     = blockIdx.x >> 5;
    const int chunk = blockIdx.x & 31;
    const int keyblk0 = b * 128 + chunk * 4;

    __shared__ float kt[64][64];
    const int t = threadIdx.x;
    #pragma unroll
    for (int u = 0; u < 2; ++u) {
        int s = 2*t + u;                       // slot < 512
        int kb4 = s >> 7, kh = (s >> 6) & 1, lane2 = s & 63;
        int g2 = lane2 >> 4, l2 = lane2 & 15;
        short8 v = *(const short8*)&KF[(size_t)(((keyblk0 + kb4) * 2 + kh) * 64 + lane2) * 8];
        #pragma unroll
        for (int j = 0; j < 8; ++j)
            kt[kb4 * 16 + l2][kh * 32 + g2 * 8 + j] = bf2f(v[j]);
    }
    __syncthreads();

    const int td = t >> 4, te = t & 15;
    float acc[4][4] = {};
    for (int j = 0; j < 64; ++j) {
        float4 a  = *(const float4*)&kt[j][td*4];
        float4 bb = *(const float4*)&kt[j][te*4];
        float av[4] = {a.x, a.y, a.z, a.w};
        float bw[4] = {bb.x, bb.y, bb.z, bb.w};
        #pragma unroll
        for (int i = 0; i < 4; ++i)
            #pragma unroll
            for (int l = 0; l < 4; ++l)
                acc[i][l] += av[i] * bw[l];
    }
    float* M = wsf + WS_M + (size_t)b * D_ * D_;
    #pragma unroll
    for (int i = 0; i < 4; ++i)
        #pragma unroll
        for (int l = 0; l < 4; ++l)
            atomicAdd(&M[(td*4 + i) * D_ + te*4 + l], acc[i][l]);

    if (t < 64) {
        float s = 0.0f;
        for (int j = 0; j < 64; ++j) s += kt[j][t];
        atomicAdd(&wsf[WS_KSUM + b * D_ + t], s);
    }
}

// ---------------------------------------------------------------------------
// 4) row stats -> a2 = inv/32*log2e, c2 = -mu*inv*log2e.  8 rows/wave.
__global__ __launch_bounds__(256) void rowstats(float* __restrict__ wsf) {
    const short* Qb = (short*)(wsf + WS_FEND) + WB_QB;
    const int t = threadIdx.x, w = t >> 6, lane = t & 63;
    const int q0 = blockIdx.x * 32 + w * 8;
    const int b  = q0 >> 11;
    const float* M = wsf + WS_M + (size_t)b * D_ * D_;

    float qv[8], y[8] = {};
    #pragma unroll
    for (int r = 0; r < 8; ++r) qv[r] = bf2f(Qb[(size_t)(q0 + r) * D_ + lane]);
    for (int d2 = 0; d2 < 64; ++d2) {
        float m = M[d2 * D_ + lane];
        #pragma unroll
        for (int r = 0; r < 8; ++r) y[r] += __shfl(qv[r], d2, 64) * m;
    }
    float kl = wsf[WS_KSUM + b * D_ + lane];
    float z[8], sv[8];
    #pragma unroll
    for (int r = 0; r < 8; ++r) { z[r] = y[r] * qv[r]; sv[r] = qv[r] * kl; }
    #pragma unroll
    for (int m = 1; m < 64; m <<= 1) {
        #pragma unroll
        for (int r = 0; r < 8; ++r) {
            z[r]  += __shfl_xor(z[r],  m, 64);
            sv[r] += __shfl_xor(sv[r], m, 64);
        }
    }
    #pragma unroll
    for (int r = 0; r < 8; ++r) {
        if (lane == r) {
            float sum   = sv[r] * (1.0f / 32.0f);
            float sumsq = z[r]  * (1.0f / 1024.0f);
            float mu  = sum * (1.0f / 2048.0f);
            float var = (sumsq - sum * sum * (1.0f / 2048.0f)) * (1.0f / 2047.0f);
            var = fmaxf(var, 0.0f);
            float inv = 1.0f / (sqrtf(var) + 1e-8f);
            wsf[WS_A2 + q0 + r] = inv * (LOG2E / 32.0f);
            wsf[WS_C2 + q0 + r] = -mu * inv * LOG2E;
        }
    }
}

// ---------------------------------------------------------------------------
// 5) MFMA flash attention.  grid (ROWS/128, KSPLIT), block 256 (4 waves).
//    K/V fragments are double-buffer staged via LDS: 16KB/chunk fetched ONCE
//    per block (was once per wave = 4x), T14 split (loads issued one chunk
//    ahead, in flight across the compute).
__global__ __launch_bounds__(256) void attention(float* __restrict__ wsf) {
    short* wsb = (short*)(wsf + WS_FEND);
    const short* Qb = wsb + WB_QB;
    const short* KF = wsb + WB_KF;
    const short* VF = wsb + WB_VF;
    __shared__ short P[4][32][72];   // per-wave [32 q][64 keys]
    __shared__ short stage[2][8192]; // dbuf: [KF 4kt*2kh*64*8][VF 4nt*2kh*64*8]

    const int t = threadIdx.x, w = t >> 6, lane = t & 63;
    const int l15 = lane & 15, g = lane >> 4;
    const int q0 = blockIdx.x * 128 + w * 32;
    const int b  = blockIdx.x >> 4;                 // 16 blocks per batch
    const int kb = blockIdx.y * (S_ / KSPLIT);      // 256-key range

    // preload Q B-frags (B[d][q]) and per-q exp2 coefficients
    bf16x8 bqf[2][2];
    float a2v[2], c2v[2];
    #pragma unroll
    for (int nt = 0; nt < 2; ++nt) {
        int q = q0 + nt*16 + l15;
        #pragma unroll
        for (int h = 0; h < 2; ++h)
            bqf[nt][h] = ldb(&Qb[(size_t)q * D_ + h*32 + g*8]);
        a2v[nt] = wsf[WS_A2 + q];
        c2v[nt] = wsf[WS_C2 + q];
    }

    floatx4 O[2][4] = {};
    float sacc[2] = {0.0f, 0.0f};
    short* Pw = &P[w][0][0];

    // reg-staged prefetch of chunk 0 (16KB split across 256 threads)
    const int tb = t * 8;
    short8 rr[4];
    {
        const short* KFc = KF + (size_t)((b * S_ + kb) >> 4) * 1024;
        const short* VFc = VF + (size_t)((b * S_ + kb) >> 6) * 4096;
        rr[0] = *(const short8*)&KFc[tb];
        rr[1] = *(const short8*)&KFc[tb + 2048];
        rr[2] = *(const short8*)&VFc[tb];
        rr[3] = *(const short8*)&VFc[tb + 2048];
    }

    for (int kc = 0; kc < S_ / KSPLIT; kc += 64) {
        short* buf = &stage[(kc >> 6) & 1][0];
        __syncthreads();                 // WAR: buf[cur] reads (chunk kc-2) done
        *(short8*)&buf[tb]        = rr[0];
        *(short8*)&buf[tb + 2048] = rr[1];
        *(short8*)&buf[tb + 4096] = rr[2];
        *(short8*)&buf[tb + 6144] = rr[3];
        if (kc + 64 < S_ / KSPLIT) {     // issue next chunk's loads (T14)
            const int key1 = kb + kc + 64;
            const short* KFc = KF + (size_t)((b * S_ + key1) >> 4) * 1024;
            const short* VFc = VF + (size_t)((b * S_ + key1) >> 6) * 4096;
            rr[0] = *(const short8*)&KFc[tb];
            rr[1] = *(const short8*)&KFc[tb + 2048];
            rr[2] = *(const short8*)&VFc[tb];
            rr[3] = *(const short8*)&VFc[tb + 2048];
        }
        __syncthreads();                 // RAW: buf[cur] staged

        // --- S^T tiles: Sc[kt][nt], D[key][q] ---
        floatx4 Sc[4][2] = {};
        #pragma unroll
        for (int kt = 0; kt < 4; ++kt) {
            bf16x8 ak0 = ldb(&buf[(kt*2 + 0)*512 + lane*8]);
            bf16x8 ak1 = ldb(&buf[(kt*2 + 1)*512 + lane*8]);
            #pragma unroll
            for (int nt = 0; nt < 2; ++nt) {
                Sc[kt][nt] = MFMA(ak0, bqf[nt][0], Sc[kt][nt]);
                Sc[kt][nt] = MFMA(ak1, bqf[nt][1], Sc[kt][nt]);
            }
        }
        lds_fence();   // WAR: previous chunk's P reads must finish
        // --- exp2 + pack bf16 + write P[q][key] ---
        #pragma unroll
        for (int nt = 0; nt < 2; ++nt) {
            const float aa = a2v[nt], cc = c2v[nt];
            #pragma unroll
            for (int kt = 0; kt < 4; ++kt) {
                float w0 = exp2f(fmaf(Sc[kt][nt][0], aa, cc));
                float w1 = exp2f(fmaf(Sc[kt][nt][1], aa, cc));
                float w2 = exp2f(fmaf(Sc[kt][nt][2], aa, cc));
                float w3 = exp2f(fmaf(Sc[kt][nt][3], aa, cc));
                sacc[nt] += (w0 + w1) + (w2 + w3);
                short4 pk;
                pk.x = bfc(w0); pk.y = bfc(w1); pk.z = bfc(w2); pk.w = bfc(w3);
                *(short4*)&Pw[(nt*16 + l15) * 72 + kt*16 + 4*g] = pk;
            }
        }
        lds_fence();   // RAW: make P visible to all lanes of this wave
        // --- PV: O[q][d] += P.V ---
        bf16x8 ap[2][2];
        #pragma unroll
        for (int mt = 0; mt < 2; ++mt)
            #pragma unroll
            for (int kh = 0; kh < 2; ++kh)
                ap[mt][kh] = ldb(&Pw[(mt*16 + l15) * 72 + kh*32 + g*8]);
        #pragma unroll
        for (int nt = 0; nt < 4; ++nt) {
            #pragma unroll
            for (int kh = 0; kh < 2; ++kh) {
                bf16x8 bv = ldb(&buf[4096 + (nt*2 + kh)*512 + lane*8]);
                #pragma unroll
                for (int mt = 0; mt < 2; ++mt)
                    O[mt][nt] = MFMA(ap[mt][kh], bv, O[mt][nt]);
            }
        }
    }

    // --- epilogue: reduce sumw over g-groups; store partials (no atomics) ---
    #pragma unroll
    for (int nt = 0; nt < 2; ++nt) {
        sacc[nt] += __shfl_xor(sacc[nt], 16, 64);
        sacc[nt] += __shfl_xor(sacc[nt], 32, 64);
    }
    if (lane < 16) {
        wsf[WS_SWP + blockIdx.y * ROWS + q0 + lane]      = sacc[0];
        wsf[WS_SWP + blockIdx.y * ROWS + q0 + 16 + lane] = sacc[1];
    }
    short* OP = wsb + WB_OP + ((size_t)blockIdx.y * ROWS + q0) * D_;
    #pragma unroll
    for (int mt = 0; mt < 2; ++mt)
        #pragma unroll
        for (int nt = 0; nt < 4; ++nt)
            #pragma unroll
            for (int r = 0; r < 4; ++r)
                OP[(size_t)(mt*16 + 4*g + r) * D_ + nt*16 + l15] =
                    (short)f2bf(O[mt][nt][r]);
}

// ---------------------------------------------------------------------------
// 6) fused reduce + output GEMM:  HN = (sum_p OP)/(sum_p SW) -> LDS A-frags;
//    out = HN @ Weff + bout.  grid ROWS/16 = 512 blocks, block 256 (4 waves).
__global__ __launch_bounds__(256) void outmm(
    const float* __restrict__ bout, const float* __restrict__ wsf,
    float* __restrict__ out)
{
    const short* wsb = (const short*)(wsf + WS_FEND);
    const short* OP  = wsb + WB_OP;
    const short* WFF = wsb + WB_WFF;
    __shared__ short hnF[2 * 64 * 8];    // A-frags of the 16-row HN tile

    const int t = threadIdx.x;
    const int row0 = blockIdx.x * 16;

    // phase 1: reduce KSPLIT partials -> normalized bf16 A-frags in LDS
    {
        const int r = t >> 4;            // 0..15 row within tile
        const int c = (t & 15) * 4;      // 0..60 col (d) group
        const int row = row0 + r;
        float sw = 0.0f;
        #pragma unroll
        for (int p = 0; p < KSPLIT; ++p) sw += wsf[WS_SWP + p * ROWS + row];
        float inv = 1.0f / sw;
        float a0 = 0.f, a1 = 0.f, a2 = 0.f, a3 = 0.f;
        #pragma unroll
        for (int p = 0; p < KSPLIT; ++p) {
            short4 o = *(const short4*)&OP[((size_t)p * ROWS + row) * D_ + c];
            a0 += bf2f(o.x); a1 += bf2f(o.y); a2 += bf2f(o.z); a3 += bf2f(o.w);
        }
        short4 hn;
        hn.x = (short)f2bf(a0 * inv); hn.y = (short)f2bf(a1 * inv);
        hn.z = (short)f2bf(a2 * inv); hn.w = (short)f2bf(a3 * inv);
        int kh = c >> 5, gH = (c >> 3) & 3, j0 = c & 7;
        *(short4*)&hnF[(size_t)(kh * 64 + gH * 16 + r) * 8 + j0] = hn;
    }
    __syncthreads();

    // phase 2: out tile [16 x 1024] = HN @ Weff + bout; wave w owns 16 n-tiles
    const int w = t >> 6, lane = t & 63, l15 = lane & 15, g = lane >> 4;
    bf16x8 ah0 = ldb(&hnF[(size_t)(0 * 64 + lane) * 8]);
    bf16x8 ah1 = ldb(&hnF[(size_t)(1 * 64 + lane) * 8]);
    #pragma unroll
    for (int i = 0; i < 16; ++i) {
        int n16 = w * 16 + i;
        floatx4 acc = {};
        acc = MFMA(ah0, ldb(&WFF[(size_t)(n16 * 2 + 0) * 512 + lane * 8]), acc);
        acc = MFMA(ah1, ldb(&WFF[(size_t)(n16 * 2 + 1) * 512 + lane * 8]), acc);
        int col = n16 * 16 + l15;
        float bb = bout[col];
        #pragma unroll
        for (int r = 0; r < 4; ++r)
            out[(size_t)(row0 + 4*g + r) * H_ + col] = acc[r] + bb;
    }
}

// ---------------------------------------------------------------------------
extern "C" void kernel_launch(void* const* d_in, const int* in_sizes, int n_in,
                              void* d_out, int out_size, void* d_ws, size_t ws_size,
                              hipStream_t stream) {
    const float* query = (const float*)d_in[0];
    const float* key   = (const float*)d_in[1];
    const float* value = (const float*)d_in[2];
    // d_in[3] mask / d_in[12] seq_mask: adding -1e-32 is a no-op in fp32 -> never read.
    const float* Wq   = (const float*)d_in[4];
    const float* bq   = (const float*)d_in[5];
    const float* Wk   = (const float*)d_in[6];
    const float* bk   = (const float*)d_in[7];
    const float* Wv   = (const float*)d_in[8];
    const float* bv   = (const float*)d_in[9];
    const float* Wout = (const float*)d_in[10];
    const float* bout = (const float*)d_in[11];

    float* ws  = (float*)d_ws;
    float* out = (float*)d_out;

    prep<<<177, 256, 0, stream>>>(Wq, Wk, Wv, Wout, ws);
    qkv_mfma<<<dim3(ROWS/32, 3), 256, 0, stream>>>(query, key, value, bq, bk, bv, ws);
    kstats<<<B_ * 32, 256, 0, stream>>>(ws);
    rowstats<<<ROWS/32, 256, 0, stream>>>(ws);
    attention<<<dim3(ROWS/128, KSPLIT), 256, 0, stream>>>(ws);
    outmm<<<ROWS/16, 256, 0, stream>>>(bout, ws, out);
}